// Round 1
// 230.901 us; speedup vs baseline: 1.0569x; 1.0569x over previous
//
#include <hip/hip_runtime.h>
#include <math.h>

#define NN 100000
#define NE 600000
#define CAP 32          // bucket capacity/node; P(Poisson(6) >= 32) ~ 1e-15
#define GN 391          // ceil(NN/256)
#define GEMMB 782       // ceil(NN/128)
#define FILLB 2344      // ceil(NE/256)
// D = 128 fixed

typedef unsigned short u16;
typedef unsigned long long u64;
typedef __attribute__((ext_vector_type(8))) short bf16x8;
typedef __attribute__((ext_vector_type(4))) float f32x4;
typedef __attribute__((ext_vector_type(2))) float f32x2;

union U16x8 { uint4 u; bf16x8 h; };

__device__ __forceinline__ float bflo(unsigned w) { return __uint_as_float(w << 16); }
__device__ __forceinline__ float bfhi(unsigned w) { return __uint_as_float(w & 0xFFFF0000u); }
__device__ __forceinline__ u16 f2bf(float f) {  // round-to-nearest-even
    unsigned u = __float_as_uint(f);
    return (u16)((u + 0x7FFFu + ((u >> 16) & 1u)) >> 16);
}
__device__ __forceinline__ unsigned pack2(float a, float b) {
    return (unsigned)f2bf(a) | ((unsigned)f2bf(b) << 16);
}
__device__ __forceinline__ f32x2 unpk2(unsigned u) {
    f32x2 r; r.x = __uint_as_float(u << 16); r.y = __uint_as_float(u & 0xFFFF0000u);
    return r;
}
// bucket entry: src(17b) << 15 | bf16-weight[14:0] (sign always 0 for ew in [0,1])
__device__ __forceinline__ float bfw(unsigned e) {
    return __uint_as_float((e & 0x7FFFu) << 16);
}
__device__ __forceinline__ int ld_idx(const int* __restrict__ ei, unsigned is32, int pos) {
    return is32 ? ei[pos] : ei[2 * pos];  // int64: little-endian low word
}

// fma-accumulate 8 bf16 channels (one uint4) scaled by WS into 4 f32x2 accs
#define ACC4(A0, A1, A2, A3, U, WS)                                     \
    {   f32x2 wv; wv.x = (WS); wv.y = (WS);                             \
        A0 = __builtin_elementwise_fma(unpk2((U).x), wv, A0);           \
        A1 = __builtin_elementwise_fma(unpk2((U).y), wv, A1);           \
        A2 = __builtin_elementwise_fma(unpk2((U).z), wv, A2);           \
        A3 = __builtin_elementwise_fma(unpk2((U).w), wv, A3); }

// ---------- W -> bf16 fragment-order block (8 blocks of 256 thr per W) ----------
// Tile (ct,kc): lane holds W[kc*32+(lane>>4)*8+j][ct*16+(lane&15)], j=0..7.
__device__ __forceinline__ void wconv_block(const float* __restrict__ W, u16* __restrict__ Wf,
                                            int blk, int tid) {
    int t = blk * 256 + tid;   // 0..2047
    int lane = t & 63, tile = t >> 6;
    int n = (tile >> 2) * 16 + (lane & 15);
    int k0 = (tile & 3) * 32 + (lane >> 4) * 8;
#pragma unroll
    for (int j = 0; j < 8; ++j) Wf[tile * 512 + lane * 8 + j] = f2bf(W[(k0 + j) * 128 + n]);
}

// ---------- init: zero cursor | detect int32-vs-int64 | wconv W1/W2 ----------
__global__ __launch_bounds__(256) void init_kernel(
    int* __restrict__ cursor, unsigned* __restrict__ flag, const unsigned* __restrict__ ei,
    const float* __restrict__ W1, const float* __restrict__ W2,
    u16* __restrict__ Wf1, u16* __restrict__ Wf2)
{
    __shared__ unsigned red[256];
    int b = blockIdx.x, tid = threadIdx.x;
    if (b < GN) {
        int i = b * 256 + tid;
        if (i < NN) cursor[i] = 0;
    } else if (b == GN) {
        unsigned v = 0;
        for (int i = tid; i < 4096; i += 256) v |= ei[2 * i + 1];
        red[tid] = v;
        __syncthreads();
        for (int o = 128; o > 0; o >>= 1) {
            if (tid < o) red[tid] |= red[tid + o];
            __syncthreads();
        }
        if (tid == 0) *flag = red[0] ? 1u : 0u;   // nonzero -> int32 storage
    } else if (b <= GN + 8) {
        wconv_block(W1, Wf1, b - GN - 1, tid);
    } else {
        wconv_block(W2, Wf2, b - GN - 9, tid);
    }
}

// ---------- fill: ONE u32 cursor atomic per edge + 4B bucket store ----------
// Runs ALONE: its cursor/bucket working set must own the L2 (r7/r12 lesson).
// ~40 us = device returning-atomic throughput floor (probed 1/thread, 2/thread, fused).
__global__ __launch_bounds__(256) void fill_kernel(
    const int* __restrict__ ei, const unsigned* __restrict__ flag,
    const float* __restrict__ ew, int* __restrict__ cursor, unsigned* __restrict__ bucket)
{
    int e = blockIdx.x * 256 + threadIdx.x;
    if (e < NE) {
        unsigned is32 = *flag;
        int s = ld_idx(ei, is32, e);
        int d = ld_idx(ei, is32, NE + e);
        unsigned wq = (unsigned)f2bf(ew[e]) & 0x7FFFu;   // bf16, sign bit 0
        int slot = atomicAdd(&cursor[d], 1);
        if (slot < CAP) bucket[(size_t)d * CAP + slot] = ((unsigned)s << 15) | wq;
    }
}

// ---------- gemm1: fused unpack (dinv from buckets) + H1 = diag(dinv) * (X @ W1) ----------
// Phase 0: 2 threads/node sum bucket weights -> dinv + clamped cursor (globals still
//          needed by both agg kernels) + 512B LDS copy for the row scale.
// Phase 1: transposed MFMA gemm as before; dn from LDS (barrier needed: tail block's
//          clamped rows cross waves). 32 nodes/wave, no other LDS use.
__global__ __launch_bounds__(256) void gemm1_kernel(
    const float* __restrict__ X, const u16* __restrict__ Wf, u16* __restrict__ H,
    int* __restrict__ cursor, const unsigned* __restrict__ bucket,
    float* __restrict__ dinv)
{
    __shared__ float Ldn[128];
    const int tid = threadIdx.x;
    const unsigned blockBase = blockIdx.x * 128u;

    {   // phase 0: weighted degree -> dinv
        unsigned ni = (unsigned)tid >> 1, p = (unsigned)tid & 1;
        unsigned gn = blockBase + ni;
        if (gn < NN) {
            int c = cursor[gn];
            if (c > CAP) c = CAP;
            float s = 0.f;
            const size_t base = (size_t)gn * CAP;
            for (int i = (int)p; i < c; i += 2) s += bfw(bucket[base + i]);
            s += __shfl_xor(s, 1);
            if (p == 0) {
                cursor[gn] = c;                  // clamp for agg kernels
                float dv = rsqrtf(s + 1.0f);
                dinv[gn] = dv;
                Ldn[ni] = dv;
            }
        }
    }
    __syncthreads();

    const int wave = tid >> 6, lane = tid & 63;
    const int m = lane & 15, q = lane >> 4;
    const unsigned nodeBase = blockBase + wave * 32;

    U16x8 xf[2][4];
    float dn[2];
#pragma unroll
    for (int mt = 0; mt < 2; ++mt) {
        unsigned row = nodeBase + mt * 16 + m;
        unsigned rowc = row < NN ? row : NN - 1;
        dn[mt] = Ldn[rowc - blockBase];
#pragma unroll
        for (int kc = 0; kc < 4; ++kc) {
            float4 a = ((const float4*)X)[rowc * 32u + kc * 8 + q * 2];
            float4 b = ((const float4*)X)[rowc * 32u + kc * 8 + q * 2 + 1];
            xf[mt][kc].u = make_uint4(pack2(a.x, a.y), pack2(a.z, a.w),
                                      pack2(b.x, b.y), pack2(b.z, b.w));
        }
    }

#pragma unroll
    for (int ct = 0; ct < 8; ++ct) {
        U16x8 wfr[4];
#pragma unroll
        for (int kc = 0; kc < 4; ++kc)
            wfr[kc].u = ((const uint4*)Wf)[(ct * 4 + kc) * 64 + lane];
#pragma unroll
        for (int mt = 0; mt < 2; ++mt) {
            f32x4 acc = (f32x4){0.f, 0.f, 0.f, 0.f};
#pragma unroll
            for (int kc = 0; kc < 4; ++kc)
                acc = __builtin_amdgcn_mfma_f32_16x16x32_bf16(
                    wfr[kc].h, xf[mt][kc].h, acc, 0, 0, 0);
            unsigned node = nodeBase + mt * 16 + m;
            if (node < NN) {
                float s = dn[mt];
                uint2 o = make_uint2(pack2(acc[0] * s, acc[1] * s),
                                     pack2(acc[2] * s, acc[3] * s));
                *(uint2*)&H[(size_t)node * 128 + ct * 16 + q * 4] = o;
            }
        }
    }
}

// ---------- agg_gemm: layer-1 aggregate (relu*dinv) -> LDS -> H2 = Xs @ W2 ----------
// Replaces agg<false> + gemmT<false>: kills the 25.6MB Xb HBM write + 25.6MB re-read.
// Each wave aggregates ITS OWN 32 rows (2-node interleave for gather MLP: all loads of
// both nodes issue before any use), stores bf16 rows to LDS, then runs the MFMA gemm on
// those same rows. No cross-wave LDS sharing -> no barrier, waves pipeline freely.
// LDS rows are 256B-strided => 16-way bank conflict on ds_read_b128; XOR-swizzle the
// uint4 column with (row&7) => 2-way (free, m136).
__global__ __launch_bounds__(256) void agg_gemm_kernel(
    const int* __restrict__ cnt, const unsigned* __restrict__ bucket,
    const u16* __restrict__ H, const float* __restrict__ dinv,
    const float* __restrict__ bias, const u16* __restrict__ Wf,
    u16* __restrict__ Hout)
{
    __shared__ uint4 Xs[2048];   // 128 rows x 16 uint4 = 32 KB
    const int tid = threadIdx.x;
    const int wave = tid >> 6, lane = tid & 63;
    const unsigned cg = lane & 15, eo = lane >> 4;
    const unsigned blockBase = blockIdx.x * 128u;
    const uint4* Hr = (const uint4*)H;

    float4 b0v = ((const float4*)bias)[cg * 2];
    float4 b1v = ((const float4*)bias)[cg * 2 + 1];

    for (int jj = 0; jj < 32; jj += 2) {
        unsigned rA = (unsigned)wave * 32u + jj;
        unsigned rB = rA + 1;
        unsigned nA = blockBase + rA, nB = blockBase + rB;
        unsigned nAc = nA < NN ? nA : NN - 1;
        unsigned nBc = nB < NN ? nB : NN - 1;

        const int cA = cnt[nAc], cB = cnt[nBc];
        const unsigned baA = nAc * CAP, baB = nBc * CAP;
        uint4 hnA = Hr[nAc * 16u + cg];
        uint4 hnB = Hr[nBc * 16u + cg];
        float dA = dinv[nAc], dB = dinv[nBc];

        unsigned eA0 = bucket[baA + eo], eA1 = bucket[baA + eo + 4], eA2 = bucket[baA + eo + 8];
        unsigned eB0 = bucket[baB + eo], eB1 = bucket[baB + eo + 4], eB2 = bucket[baB + eo + 8];
        bool vA0 = (int)eo < cA, vA1 = (int)eo + 4 < cA, vA2 = (int)eo + 8 < cA;
        bool vB0 = (int)eo < cB, vB1 = (int)eo + 4 < cB, vB2 = (int)eo + 8 < cB;
        float wA0 = vA0 ? bfw(eA0) : 0.f, wA1 = vA1 ? bfw(eA1) : 0.f, wA2 = vA2 ? bfw(eA2) : 0.f;
        float wB0 = vB0 ? bfw(eB0) : 0.f, wB1 = vB1 ? bfw(eB1) : 0.f, wB2 = vB2 ? bfw(eB2) : 0.f;
        unsigned sA0 = vA0 ? (eA0 >> 15) : nAc, sA1 = vA1 ? (eA1 >> 15) : nAc,
                 sA2 = vA2 ? (eA2 >> 15) : nAc;
        unsigned sB0 = vB0 ? (eB0 >> 15) : nBc, sB1 = vB1 ? (eB1 >> 15) : nBc,
                 sB2 = vB2 ? (eB2 >> 15) : nBc;
        uint4 uA0 = Hr[sA0 * 16u + cg], uA1 = Hr[sA1 * 16u + cg], uA2 = Hr[sA2 * 16u + cg];
        uint4 uB0 = Hr[sB0 * 16u + cg], uB1 = Hr[sB1 * 16u + cg], uB2 = Hr[sB2 * 16u + cg];

        f32x2 aA0 = {0.f,0.f}, aA1 = {0.f,0.f}, aA2 = {0.f,0.f}, aA3 = {0.f,0.f};
        f32x2 aB0 = {0.f,0.f}, aB1 = {0.f,0.f}, aB2 = {0.f,0.f}, aB3 = {0.f,0.f};
        ACC4(aA0, aA1, aA2, aA3, uA0, wA0)
        ACC4(aA0, aA1, aA2, aA3, uA1, wA1)
        ACC4(aA0, aA1, aA2, aA3, uA2, wA2)
        ACC4(aB0, aB1, aB2, aB3, uB0, wB0)
        ACC4(aB0, aB1, aB2, aB3, uB1, wB1)
        ACC4(aB0, aB1, aB2, aB3, uB2, wB2)

        if (cA > 12) {                // rare tail (~1% of nodes)
            for (int i = (int)eo + 12; i < cA; i += 4) {
                unsigned e = bucket[baA + i];
                float w = bfw(e);
                uint4 u = Hr[(e >> 15) * 16u + cg];
                ACC4(aA0, aA1, aA2, aA3, u, w)
            }
        }
        if (cB > 12) {
            for (int i = (int)eo + 12; i < cB; i += 4) {
                unsigned e = bucket[baB + i];
                float w = bfw(e);
                uint4 u = Hr[(e >> 15) * 16u + cg];
                ACC4(aB0, aB1, aB2, aB3, u, w)
            }
        }

        float accA[8] = {aA0.x, aA0.y, aA1.x, aA1.y, aA2.x, aA2.y, aA3.x, aA3.y};
        float accB[8] = {aB0.x, aB0.y, aB1.x, aB1.y, aB2.x, aB2.y, aB3.x, aB3.y};
#pragma unroll
        for (int j = 0; j < 8; ++j) {
            accA[j] += __shfl_down(accA[j], 32);
            accB[j] += __shfl_down(accB[j], 32);
            accA[j] += __shfl_down(accA[j], 16);
            accB[j] += __shfl_down(accB[j], 16);
        }

        if (lane < 16) {
            accA[0] += bflo(hnA.x); accA[1] += bfhi(hnA.x);
            accA[2] += bflo(hnA.y); accA[3] += bfhi(hnA.y);
            accA[4] += bflo(hnA.z); accA[5] += bfhi(hnA.z);
            accA[6] += bflo(hnA.w); accA[7] += bfhi(hnA.w);
            float v0 = fmaxf(fmaf(dA, accA[0], b0v.x), 0.f);
            float v1 = fmaxf(fmaf(dA, accA[1], b0v.y), 0.f);
            float v2 = fmaxf(fmaf(dA, accA[2], b0v.z), 0.f);
            float v3 = fmaxf(fmaf(dA, accA[3], b0v.w), 0.f);
            float v4 = fmaxf(fmaf(dA, accA[4], b1v.x), 0.f);
            float v5 = fmaxf(fmaf(dA, accA[5], b1v.y), 0.f);
            float v6 = fmaxf(fmaf(dA, accA[6], b1v.z), 0.f);
            float v7 = fmaxf(fmaf(dA, accA[7], b1v.w), 0.f);
            uint4 o;
            o.x = pack2(v0 * dA, v1 * dA); o.y = pack2(v2 * dA, v3 * dA);
            o.z = pack2(v4 * dA, v5 * dA); o.w = pack2(v6 * dA, v7 * dA);
            Xs[rA * 16u + (cg ^ (rA & 7u))] = o;

            accB[0] += bflo(hnB.x); accB[1] += bfhi(hnB.x);
            accB[2] += bflo(hnB.y); accB[3] += bfhi(hnB.y);
            accB[4] += bflo(hnB.z); accB[5] += bfhi(hnB.z);
            accB[6] += bflo(hnB.w); accB[7] += bfhi(hnB.w);
            v0 = fmaxf(fmaf(dB, accB[0], b0v.x), 0.f);
            v1 = fmaxf(fmaf(dB, accB[1], b0v.y), 0.f);
            v2 = fmaxf(fmaf(dB, accB[2], b0v.z), 0.f);
            v3 = fmaxf(fmaf(dB, accB[3], b0v.w), 0.f);
            v4 = fmaxf(fmaf(dB, accB[4], b1v.x), 0.f);
            v5 = fmaxf(fmaf(dB, accB[5], b1v.y), 0.f);
            v6 = fmaxf(fmaf(dB, accB[6], b1v.z), 0.f);
            v7 = fmaxf(fmaf(dB, accB[7], b1v.w), 0.f);
            o.x = pack2(v0 * dB, v1 * dB); o.y = pack2(v2 * dB, v3 * dB);
            o.z = pack2(v4 * dB, v5 * dB); o.w = pack2(v6 * dB, v7 * dB);
            Xs[rB * 16u + (cg ^ (rB & 7u))] = o;
        }
    }
    // no __syncthreads: each wave reads only the 32 rows it wrote (in-wave lgkmcnt order)

    const int m = lane & 15, q = lane >> 4;
    U16x8 xf[2][4];
#pragma unroll
    for (int mt = 0; mt < 2; ++mt) {
        unsigned r = (unsigned)wave * 32u + mt * 16 + m;
#pragma unroll
        for (int kc = 0; kc < 4; ++kc)
            xf[mt][kc].u = Xs[r * 16u + ((unsigned)(kc * 4 + q) ^ (r & 7u))];
    }
#pragma unroll
    for (int ct = 0; ct < 8; ++ct) {
        U16x8 wfr[4];
#pragma unroll
        for (int kc = 0; kc < 4; ++kc)
            wfr[kc].u = ((const uint4*)Wf)[(ct * 4 + kc) * 64 + lane];
#pragma unroll
        for (int mt = 0; mt < 2; ++mt) {
            f32x4 acc = (f32x4){0.f, 0.f, 0.f, 0.f};
#pragma unroll
            for (int kc = 0; kc < 4; ++kc)
                acc = __builtin_amdgcn_mfma_f32_16x16x32_bf16(
                    wfr[kc].h, xf[mt][kc].h, acc, 0, 0, 0);
            unsigned node = blockBase + (unsigned)wave * 32u + mt * 16 + m;
            if (node < NN) {
                uint2 o = make_uint2(pack2(acc[0], acc[1]), pack2(acc[2], acc[3]));
                *(uint2*)&Hout[(size_t)node * 128 + ct * 16 + q * 4] = o;
            }
        }
    }
}

// ---------- agg head: 1 wave/node, straight-line 3 slots (deg<=12) + rare tail ----------
// out[n] = relu(dinv[n]*(sum w*H2[src] + H2[n]) + b2) . Wl + bl
__global__ __launch_bounds__(256) void agg_head_kernel(
    const int* __restrict__ cnt, const unsigned* __restrict__ bucket,
    const u16* __restrict__ H, const float* __restrict__ dinv,
    const float* __restrict__ bias, const float* __restrict__ Wl,
    const float* __restrict__ bl, float* __restrict__ out)
{
    unsigned t = blockIdx.x * 256 + threadIdx.x;
    unsigned n = t >> 6;
    unsigned lane = t & 63;
    unsigned cg = lane & 15;
    unsigned eo = lane >> 4;

    const int c = cnt[n];
    const unsigned base = n * CAP;
    const uint4* Hr = (const uint4*)H;

    uint4 hn = Hr[n * 16u + cg];
    float dnv = dinv[n];

    unsigned e0 = bucket[base + eo];
    unsigned e1 = bucket[base + eo + 4];
    unsigned e2 = bucket[base + eo + 8];
    bool v0 = (int)eo < c, v1 = (int)eo + 4 < c, v2 = (int)eo + 8 < c;
    float w0 = v0 ? bfw(e0) : 0.f;
    float w1 = v1 ? bfw(e1) : 0.f;
    float w2 = v2 ? bfw(e2) : 0.f;
    unsigned s0 = v0 ? (e0 >> 15) : n;
    unsigned s1 = v1 ? (e1 >> 15) : n;
    unsigned s2 = v2 ? (e2 >> 15) : n;
    uint4 u0 = Hr[s0 * 16u + cg];
    uint4 u1 = Hr[s1 * 16u + cg];
    uint4 u2 = Hr[s2 * 16u + cg];

    f32x2 a0 = {0.f, 0.f}, a1 = {0.f, 0.f}, a2 = {0.f, 0.f}, a3 = {0.f, 0.f};
    ACC4(a0, a1, a2, a3, u0, w0)
    ACC4(a0, a1, a2, a3, u1, w1)
    ACC4(a0, a1, a2, a3, u2, w2)

    if (c > 12) {                 // rare tail (~1% of nodes)
        for (int i = (int)eo + 12; i < c; i += 4) {
            unsigned e = bucket[base + i];
            float w = bfw(e);
            uint4 u = Hr[(e >> 15) * 16u + cg];
            ACC4(a0, a1, a2, a3, u, w)
        }
    }

    float acc[8] = {a0.x, a0.y, a1.x, a1.y, a2.x, a2.y, a3.x, a3.y};
#pragma unroll
    for (int j = 0; j < 8; ++j) {
        acc[j] += __shfl_down(acc[j], 32);
        acc[j] += __shfl_down(acc[j], 16);
    }

    float d = 0.f;
    if (lane < 16) {
        float4 b0 = ((const float4*)bias)[cg * 2];
        float4 b1 = ((const float4*)bias)[cg * 2 + 1];
        acc[0] += bflo(hn.x); acc[1] += bfhi(hn.x);
        acc[2] += bflo(hn.y); acc[3] += bfhi(hn.y);
        acc[4] += bflo(hn.z); acc[5] += bfhi(hn.z);
        acc[6] += bflo(hn.w); acc[7] += bfhi(hn.w);
        float v[8];
        v[0] = fmaxf(fmaf(dnv, acc[0], b0.x), 0.f);
        v[1] = fmaxf(fmaf(dnv, acc[1], b0.y), 0.f);
        v[2] = fmaxf(fmaf(dnv, acc[2], b0.z), 0.f);
        v[3] = fmaxf(fmaf(dnv, acc[3], b0.w), 0.f);
        v[4] = fmaxf(fmaf(dnv, acc[4], b1.x), 0.f);
        v[5] = fmaxf(fmaf(dnv, acc[5], b1.y), 0.f);
        v[6] = fmaxf(fmaf(dnv, acc[6], b1.z), 0.f);
        v[7] = fmaxf(fmaf(dnv, acc[7], b1.w), 0.f);
        float4 w0v = ((const float4*)Wl)[cg * 2];
        float4 w1v = ((const float4*)Wl)[cg * 2 + 1];
        d = v[0] * w0v.x + v[1] * w0v.y + v[2] * w0v.z + v[3] * w0v.w
          + v[4] * w1v.x + v[5] * w1v.y + v[6] * w1v.z + v[7] * w1v.w;
#pragma unroll
        for (int off = 8; off > 0; off >>= 1) d += __shfl_down(d, off, 16);
        if (lane == 0) out[n] = d + bl[0];
    }
}

extern "C" void kernel_launch(void* const* d_in, const int* in_sizes, int n_in,
                              void* d_out, int out_size, void* d_ws, size_t ws_size,
                              hipStream_t stream) {
    const float* w_x = (const float*)d_in[0];
    const int*   ei  = (const int*)d_in[1];
    const float* ew  = (const float*)d_in[2];
    const float* W1  = (const float*)d_in[3];
    const float* b1  = (const float*)d_in[4];
    const float* W2  = (const float*)d_in[5];
    const float* b2  = (const float*)d_in[6];
    const float* Wl  = (const float*)d_in[7];
    const float* bl  = (const float*)d_in[8];
    float* out = (float*)d_out;

    // ws: H1[NN*128 bf16] H2[NN*128 bf16] flag(+pad) dinv[NN]
    //     cursor[NN] bucket[NN*CAP u32] Wf1/Wf2[16384 u16]   (~65 MB)
    u16*      H1   = (u16*)d_ws;
    u16*      H2   = H1 + (size_t)NN * 128;
    unsigned* flag = (unsigned*)(H2 + (size_t)NN * 128);
    float*    dinv = (float*)(flag + 2);
    int*      cursor = (int*)(dinv + NN);
    unsigned* bucket = (unsigned*)(cursor + NN);
    u16*      Wf1  = (u16*)(bucket + (size_t)NN * CAP);
    u16*      Wf2  = Wf1 + 16384;

    const int BLK = 256;
    const int GA  = NN * 64 / BLK;     // 25000 head-agg blocks

    init_kernel<<<GN + 17, BLK, 0, stream>>>(cursor, flag, (const unsigned*)ei,
                                             W1, W2, Wf1, Wf2);
    fill_kernel<<<FILLB, BLK, 0, stream>>>(ei, flag, ew, cursor, bucket);
    gemm1_kernel<<<GEMMB, BLK, 0, stream>>>(w_x, Wf1, H1, cursor, bucket, dinv);
    agg_gemm_kernel<<<GEMMB, BLK, 0, stream>>>(cursor, bucket, H1, dinv, b1, Wf2, H2);
    agg_head_kernel<<<GA, BLK, 0, stream>>>(cursor, bucket, H2, dinv, b2, Wl, bl, out);
}

// Round 2
// 229.499 us; speedup vs baseline: 1.0633x; 1.0061x over previous
//
#include <hip/hip_runtime.h>
#include <math.h>

#define NN 100000
#define NE 600000
#define CAP 32          // bucket capacity/node; P(Poisson(6) >= 32) ~ 1e-15
#define GN 391          // ceil(NN/256)
#define GEMMB 782       // ceil(NN/128)
#define AGB 1563        // ceil(NN/64)  -- agg_gemm: 64 nodes/block for 6 waves/SIMD
#define FILLB 2344      // ceil(NE/256)
// D = 128 fixed

typedef unsigned short u16;
typedef unsigned long long u64;
typedef __attribute__((ext_vector_type(8))) short bf16x8;
typedef __attribute__((ext_vector_type(4))) float f32x4;
typedef __attribute__((ext_vector_type(2))) float f32x2;

union U16x8 { uint4 u; bf16x8 h; };

__device__ __forceinline__ float bflo(unsigned w) { return __uint_as_float(w << 16); }
__device__ __forceinline__ float bfhi(unsigned w) { return __uint_as_float(w & 0xFFFF0000u); }
__device__ __forceinline__ u16 f2bf(float f) {  // round-to-nearest-even
    unsigned u = __float_as_uint(f);
    return (u16)((u + 0x7FFFu + ((u >> 16) & 1u)) >> 16);
}
__device__ __forceinline__ unsigned pack2(float a, float b) {
    return (unsigned)f2bf(a) | ((unsigned)f2bf(b) << 16);
}
__device__ __forceinline__ f32x2 unpk2(unsigned u) {
    f32x2 r; r.x = __uint_as_float(u << 16); r.y = __uint_as_float(u & 0xFFFF0000u);
    return r;
}
// bucket entry: src(17b) << 15 | bf16-weight[14:0] (sign always 0 for ew in [0,1])
__device__ __forceinline__ float bfw(unsigned e) {
    return __uint_as_float((e & 0x7FFFu) << 16);
}
__device__ __forceinline__ int ld_idx(const int* __restrict__ ei, unsigned is32, int pos) {
    return is32 ? ei[pos] : ei[2 * pos];  // int64: little-endian low word
}

// fma-accumulate 8 bf16 channels (one uint4) scaled by WS into 4 f32x2 accs
#define ACC4(A0, A1, A2, A3, U, WS)                                     \
    {   f32x2 wv; wv.x = (WS); wv.y = (WS);                             \
        A0 = __builtin_elementwise_fma(unpk2((U).x), wv, A0);           \
        A1 = __builtin_elementwise_fma(unpk2((U).y), wv, A1);           \
        A2 = __builtin_elementwise_fma(unpk2((U).z), wv, A2);           \
        A3 = __builtin_elementwise_fma(unpk2((U).w), wv, A3); }

// ---------- W -> bf16 fragment-order block (8 blocks of 256 thr per W) ----------
// Tile (ct,kc): lane holds W[kc*32+(lane>>4)*8+j][ct*16+(lane&15)], j=0..7.
__device__ __forceinline__ void wconv_block(const float* __restrict__ W, u16* __restrict__ Wf,
                                            int blk, int tid) {
    int t = blk * 256 + tid;   // 0..2047
    int lane = t & 63, tile = t >> 6;
    int n = (tile >> 2) * 16 + (lane & 15);
    int k0 = (tile & 3) * 32 + (lane >> 4) * 8;
#pragma unroll
    for (int j = 0; j < 8; ++j) Wf[tile * 512 + lane * 8 + j] = f2bf(W[(k0 + j) * 128 + n]);
}

// ---------- init: zero cursor | detect int32-vs-int64 | wconv W1/W2 ----------
__global__ __launch_bounds__(256) void init_kernel(
    int* __restrict__ cursor, unsigned* __restrict__ flag, const unsigned* __restrict__ ei,
    const float* __restrict__ W1, const float* __restrict__ W2,
    u16* __restrict__ Wf1, u16* __restrict__ Wf2)
{
    __shared__ unsigned red[256];
    int b = blockIdx.x, tid = threadIdx.x;
    if (b < GN) {
        int i = b * 256 + tid;
        if (i < NN) cursor[i] = 0;
    } else if (b == GN) {
        unsigned v = 0;
        for (int i = tid; i < 4096; i += 256) v |= ei[2 * i + 1];
        red[tid] = v;
        __syncthreads();
        for (int o = 128; o > 0; o >>= 1) {
            if (tid < o) red[tid] |= red[tid + o];
            __syncthreads();
        }
        if (tid == 0) *flag = red[0] ? 1u : 0u;   // nonzero -> int32 storage
    } else if (b <= GN + 8) {
        wconv_block(W1, Wf1, b - GN - 1, tid);
    } else {
        wconv_block(W2, Wf2, b - GN - 9, tid);
    }
}

// ---------- fill: ONE u32 cursor atomic per edge + 4B bucket store ----------
// Runs ALONE: its cursor/bucket working set must own the L2 (r7/r12 lesson).
// ~40 us = device returning-atomic throughput floor (probed 1/thread, 2/thread, fused).
__global__ __launch_bounds__(256) void fill_kernel(
    const int* __restrict__ ei, const unsigned* __restrict__ flag,
    const float* __restrict__ ew, int* __restrict__ cursor, unsigned* __restrict__ bucket)
{
    int e = blockIdx.x * 256 + threadIdx.x;
    if (e < NE) {
        unsigned is32 = *flag;
        int s = ld_idx(ei, is32, e);
        int d = ld_idx(ei, is32, NE + e);
        unsigned wq = (unsigned)f2bf(ew[e]) & 0x7FFFu;   // bf16, sign bit 0
        int slot = atomicAdd(&cursor[d], 1);
        if (slot < CAP) bucket[(size_t)d * CAP + slot] = ((unsigned)s << 15) | wq;
    }
}

// ---------- gemm1: fused unpack (dinv from buckets) + H1 = diag(dinv) * (X @ W1) ----------
// Phase 0: 2 threads/node sum bucket weights -> dinv + clamped cursor (globals still
//          needed by both agg kernels) + 512B LDS copy for the row scale.
// Phase 1: transposed MFMA gemm; dn from LDS. 32 nodes/wave (probed optimum for the
//          pure coalesced-input gemm; do NOT shrink -- doubles Wf traffic at no
//          latency benefit since X reads are streaming, not gathered).
__global__ __launch_bounds__(256) void gemm1_kernel(
    const float* __restrict__ X, const u16* __restrict__ Wf, u16* __restrict__ H,
    int* __restrict__ cursor, const unsigned* __restrict__ bucket,
    float* __restrict__ dinv)
{
    __shared__ float Ldn[128];
    const int tid = threadIdx.x;
    const unsigned blockBase = blockIdx.x * 128u;

    {   // phase 0: weighted degree -> dinv
        unsigned ni = (unsigned)tid >> 1, p = (unsigned)tid & 1;
        unsigned gn = blockBase + ni;
        if (gn < NN) {
            int c = cursor[gn];
            if (c > CAP) c = CAP;
            float s = 0.f;
            const size_t base = (size_t)gn * CAP;
            for (int i = (int)p; i < c; i += 2) s += bfw(bucket[base + i]);
            s += __shfl_xor(s, 1);
            if (p == 0) {
                cursor[gn] = c;                  // clamp for agg kernels
                float dv = rsqrtf(s + 1.0f);
                dinv[gn] = dv;
                Ldn[ni] = dv;
            }
        }
    }
    __syncthreads();

    const int wave = tid >> 6, lane = tid & 63;
    const int m = lane & 15, q = lane >> 4;
    const unsigned nodeBase = blockBase + wave * 32;

    U16x8 xf[2][4];
    float dn[2];
#pragma unroll
    for (int mt = 0; mt < 2; ++mt) {
        unsigned row = nodeBase + mt * 16 + m;
        unsigned rowc = row < NN ? row : NN - 1;
        dn[mt] = Ldn[rowc - blockBase];
#pragma unroll
        for (int kc = 0; kc < 4; ++kc) {
            float4 a = ((const float4*)X)[rowc * 32u + kc * 8 + q * 2];
            float4 b = ((const float4*)X)[rowc * 32u + kc * 8 + q * 2 + 1];
            xf[mt][kc].u = make_uint4(pack2(a.x, a.y), pack2(a.z, a.w),
                                      pack2(b.x, b.y), pack2(b.z, b.w));
        }
    }

#pragma unroll
    for (int ct = 0; ct < 8; ++ct) {
        U16x8 wfr[4];
#pragma unroll
        for (int kc = 0; kc < 4; ++kc)
            wfr[kc].u = ((const uint4*)Wf)[(ct * 4 + kc) * 64 + lane];
#pragma unroll
        for (int mt = 0; mt < 2; ++mt) {
            f32x4 acc = (f32x4){0.f, 0.f, 0.f, 0.f};
#pragma unroll
            for (int kc = 0; kc < 4; ++kc)
                acc = __builtin_amdgcn_mfma_f32_16x16x32_bf16(
                    wfr[kc].h, xf[mt][kc].h, acc, 0, 0, 0);
            unsigned node = nodeBase + mt * 16 + m;
            if (node < NN) {
                float s = dn[mt];
                uint2 o = make_uint2(pack2(acc[0] * s, acc[1] * s),
                                     pack2(acc[2] * s, acc[3] * s));
                *(uint2*)&H[(size_t)node * 128 + ct * 16 + q * 4] = o;
            }
        }
    }
}

// ---------- agg_gemm: layer-1 aggregate (relu*dinv) -> LDS -> H2 = Xs @ W2 ----------
// R1: 64 nodes/block, 16 nodes/wave (M-tile=1). The R0 128-node version was GRID-
// STARVED: 782 blocks x 4 waves = 3 waves/SIMD, gather latency exposed (Occ 24%,
// HBM 27%, dur 53us). 1563 blocks -> 6.1 waves/SIMD. Cost: Wf re-read doubles
// (+100MB L2-resident, ~3us overlapped) -- a good trade ONLY because the agg phase
// is a dependent-gather chain; the pure gemm keeps 32/wave (see gemm1).
// Each wave aggregates ITS OWN 16 rows (2-node interleave), stores bf16 rows to LDS,
// then runs the MFMA gemm on those same rows. No cross-wave sharing -> no barrier.
// LDS rows 256B-strided => XOR-swizzle uint4 column with (row&7) => ~2-way (free).
__global__ __launch_bounds__(256) void agg_gemm_kernel(
    const int* __restrict__ cnt, const unsigned* __restrict__ bucket,
    const u16* __restrict__ H, const float* __restrict__ dinv,
    const float* __restrict__ bias, const u16* __restrict__ Wf,
    u16* __restrict__ Hout)
{
    __shared__ uint4 Xs[1024];   // 64 rows x 16 uint4 = 16 KB
    const int tid = threadIdx.x;
    const int wave = tid >> 6, lane = tid & 63;
    const unsigned cg = lane & 15, eo = lane >> 4;
    const unsigned blockBase = blockIdx.x * 64u;
    const uint4* Hr = (const uint4*)H;

    float4 b0v = ((const float4*)bias)[cg * 2];
    float4 b1v = ((const float4*)bias)[cg * 2 + 1];

    for (int jj = 0; jj < 16; jj += 2) {
        unsigned rA = (unsigned)wave * 16u + jj;
        unsigned rB = rA + 1;
        unsigned nA = blockBase + rA, nB = blockBase + rB;
        unsigned nAc = nA < NN ? nA : NN - 1;
        unsigned nBc = nB < NN ? nB : NN - 1;

        const int cA = cnt[nAc], cB = cnt[nBc];
        const unsigned baA = nAc * CAP, baB = nBc * CAP;
        uint4 hnA = Hr[nAc * 16u + cg];
        uint4 hnB = Hr[nBc * 16u + cg];
        float dA = dinv[nAc], dB = dinv[nBc];

        unsigned eA0 = bucket[baA + eo], eA1 = bucket[baA + eo + 4], eA2 = bucket[baA + eo + 8];
        unsigned eB0 = bucket[baB + eo], eB1 = bucket[baB + eo + 4], eB2 = bucket[baB + eo + 8];
        bool vA0 = (int)eo < cA, vA1 = (int)eo + 4 < cA, vA2 = (int)eo + 8 < cA;
        bool vB0 = (int)eo < cB, vB1 = (int)eo + 4 < cB, vB2 = (int)eo + 8 < cB;
        float wA0 = vA0 ? bfw(eA0) : 0.f, wA1 = vA1 ? bfw(eA1) : 0.f, wA2 = vA2 ? bfw(eA2) : 0.f;
        float wB0 = vB0 ? bfw(eB0) : 0.f, wB1 = vB1 ? bfw(eB1) : 0.f, wB2 = vB2 ? bfw(eB2) : 0.f;
        unsigned sA0 = vA0 ? (eA0 >> 15) : nAc, sA1 = vA1 ? (eA1 >> 15) : nAc,
                 sA2 = vA2 ? (eA2 >> 15) : nAc;
        unsigned sB0 = vB0 ? (eB0 >> 15) : nBc, sB1 = vB1 ? (eB1 >> 15) : nBc,
                 sB2 = vB2 ? (eB2 >> 15) : nBc;
        uint4 uA0 = Hr[sA0 * 16u + cg], uA1 = Hr[sA1 * 16u + cg], uA2 = Hr[sA2 * 16u + cg];
        uint4 uB0 = Hr[sB0 * 16u + cg], uB1 = Hr[sB1 * 16u + cg], uB2 = Hr[sB2 * 16u + cg];

        f32x2 aA0 = {0.f,0.f}, aA1 = {0.f,0.f}, aA2 = {0.f,0.f}, aA3 = {0.f,0.f};
        f32x2 aB0 = {0.f,0.f}, aB1 = {0.f,0.f}, aB2 = {0.f,0.f}, aB3 = {0.f,0.f};
        ACC4(aA0, aA1, aA2, aA3, uA0, wA0)
        ACC4(aA0, aA1, aA2, aA3, uA1, wA1)
        ACC4(aA0, aA1, aA2, aA3, uA2, wA2)
        ACC4(aB0, aB1, aB2, aB3, uB0, wB0)
        ACC4(aB0, aB1, aB2, aB3, uB1, wB1)
        ACC4(aB0, aB1, aB2, aB3, uB2, wB2)

        if (cA > 12) {                // rare tail (~1% of nodes)
            for (int i = (int)eo + 12; i < cA; i += 4) {
                unsigned e = bucket[baA + i];
                float w = bfw(e);
                uint4 u = Hr[(e >> 15) * 16u + cg];
                ACC4(aA0, aA1, aA2, aA3, u, w)
            }
        }
        if (cB > 12) {
            for (int i = (int)eo + 12; i < cB; i += 4) {
                unsigned e = bucket[baB + i];
                float w = bfw(e);
                uint4 u = Hr[(e >> 15) * 16u + cg];
                ACC4(aB0, aB1, aB2, aB3, u, w)
            }
        }

        float accA[8] = {aA0.x, aA0.y, aA1.x, aA1.y, aA2.x, aA2.y, aA3.x, aA3.y};
        float accB[8] = {aB0.x, aB0.y, aB1.x, aB1.y, aB2.x, aB2.y, aB3.x, aB3.y};
#pragma unroll
        for (int j = 0; j < 8; ++j) {
            accA[j] += __shfl_down(accA[j], 32);
            accB[j] += __shfl_down(accB[j], 32);
            accA[j] += __shfl_down(accA[j], 16);
            accB[j] += __shfl_down(accB[j], 16);
        }

        if (lane < 16) {
            accA[0] += bflo(hnA.x); accA[1] += bfhi(hnA.x);
            accA[2] += bflo(hnA.y); accA[3] += bfhi(hnA.y);
            accA[4] += bflo(hnA.z); accA[5] += bfhi(hnA.z);
            accA[6] += bflo(hnA.w); accA[7] += bfhi(hnA.w);
            float v0 = fmaxf(fmaf(dA, accA[0], b0v.x), 0.f);
            float v1 = fmaxf(fmaf(dA, accA[1], b0v.y), 0.f);
            float v2 = fmaxf(fmaf(dA, accA[2], b0v.z), 0.f);
            float v3 = fmaxf(fmaf(dA, accA[3], b0v.w), 0.f);
            float v4 = fmaxf(fmaf(dA, accA[4], b1v.x), 0.f);
            float v5 = fmaxf(fmaf(dA, accA[5], b1v.y), 0.f);
            float v6 = fmaxf(fmaf(dA, accA[6], b1v.z), 0.f);
            float v7 = fmaxf(fmaf(dA, accA[7], b1v.w), 0.f);
            uint4 o;
            o.x = pack2(v0 * dA, v1 * dA); o.y = pack2(v2 * dA, v3 * dA);
            o.z = pack2(v4 * dA, v5 * dA); o.w = pack2(v6 * dA, v7 * dA);
            Xs[rA * 16u + (cg ^ (rA & 7u))] = o;

            accB[0] += bflo(hnB.x); accB[1] += bfhi(hnB.x);
            accB[2] += bflo(hnB.y); accB[3] += bfhi(hnB.y);
            accB[4] += bflo(hnB.z); accB[5] += bfhi(hnB.z);
            accB[6] += bflo(hnB.w); accB[7] += bfhi(hnB.w);
            v0 = fmaxf(fmaf(dB, accB[0], b0v.x), 0.f);
            v1 = fmaxf(fmaf(dB, accB[1], b0v.y), 0.f);
            v2 = fmaxf(fmaf(dB, accB[2], b0v.z), 0.f);
            v3 = fmaxf(fmaf(dB, accB[3], b0v.w), 0.f);
            v4 = fmaxf(fmaf(dB, accB[4], b1v.x), 0.f);
            v5 = fmaxf(fmaf(dB, accB[5], b1v.y), 0.f);
            v6 = fmaxf(fmaf(dB, accB[6], b1v.z), 0.f);
            v7 = fmaxf(fmaf(dB, accB[7], b1v.w), 0.f);
            o.x = pack2(v0 * dB, v1 * dB); o.y = pack2(v2 * dB, v3 * dB);
            o.z = pack2(v4 * dB, v5 * dB); o.w = pack2(v6 * dB, v7 * dB);
            Xs[rB * 16u + (cg ^ (rB & 7u))] = o;
        }
    }
    // no __syncthreads: each wave reads only the 16 rows it wrote (in-wave lgkmcnt order)

    const int m = lane & 15, q = lane >> 4;
    U16x8 xf[4];
    {
        unsigned r = (unsigned)wave * 16u + m;
#pragma unroll
        for (int kc = 0; kc < 4; ++kc)
            xf[kc].u = Xs[r * 16u + ((unsigned)(kc * 4 + q) ^ (r & 7u))];
    }
#pragma unroll
    for (int ct = 0; ct < 8; ++ct) {
        U16x8 wfr[4];
#pragma unroll
        for (int kc = 0; kc < 4; ++kc)
            wfr[kc].u = ((const uint4*)Wf)[(ct * 4 + kc) * 64 + lane];
        f32x4 acc = (f32x4){0.f, 0.f, 0.f, 0.f};
#pragma unroll
        for (int kc = 0; kc < 4; ++kc)
            acc = __builtin_amdgcn_mfma_f32_16x16x32_bf16(
                wfr[kc].h, xf[kc].h, acc, 0, 0, 0);
        unsigned node = blockBase + (unsigned)wave * 16u + m;
        if (node < NN) {
            uint2 o = make_uint2(pack2(acc[0], acc[1]), pack2(acc[2], acc[3]));
            *(uint2*)&Hout[(size_t)node * 128 + ct * 16 + q * 4] = o;
        }
    }
}

// ---------- agg head: 1 wave/node, straight-line 3 slots (deg<=12) + rare tail ----------
// out[n] = relu(dinv[n]*(sum w*H2[src] + H2[n]) + b2) . Wl + bl
__global__ __launch_bounds__(256) void agg_head_kernel(
    const int* __restrict__ cnt, const unsigned* __restrict__ bucket,
    const u16* __restrict__ H, const float* __restrict__ dinv,
    const float* __restrict__ bias, const float* __restrict__ Wl,
    const float* __restrict__ bl, float* __restrict__ out)
{
    unsigned t = blockIdx.x * 256 + threadIdx.x;
    unsigned n = t >> 6;
    unsigned lane = t & 63;
    unsigned cg = lane & 15;
    unsigned eo = lane >> 4;

    const int c = cnt[n];
    const unsigned base = n * CAP;
    const uint4* Hr = (const uint4*)H;

    uint4 hn = Hr[n * 16u + cg];
    float dnv = dinv[n];

    unsigned e0 = bucket[base + eo];
    unsigned e1 = bucket[base + eo + 4];
    unsigned e2 = bucket[base + eo + 8];
    bool v0 = (int)eo < c, v1 = (int)eo + 4 < c, v2 = (int)eo + 8 < c;
    float w0 = v0 ? bfw(e0) : 0.f;
    float w1 = v1 ? bfw(e1) : 0.f;
    float w2 = v2 ? bfw(e2) : 0.f;
    unsigned s0 = v0 ? (e0 >> 15) : n;
    unsigned s1 = v1 ? (e1 >> 15) : n;
    unsigned s2 = v2 ? (e2 >> 15) : n;
    uint4 u0 = Hr[s0 * 16u + cg];
    uint4 u1 = Hr[s1 * 16u + cg];
    uint4 u2 = Hr[s2 * 16u + cg];

    f32x2 a0 = {0.f, 0.f}, a1 = {0.f, 0.f}, a2 = {0.f, 0.f}, a3 = {0.f, 0.f};
    ACC4(a0, a1, a2, a3, u0, w0)
    ACC4(a0, a1, a2, a3, u1, w1)
    ACC4(a0, a1, a2, a3, u2, w2)

    if (c > 12) {                 // rare tail (~1% of nodes)
        for (int i = (int)eo + 12; i < c; i += 4) {
            unsigned e = bucket[base + i];
            float w = bfw(e);
            uint4 u = Hr[(e >> 15) * 16u + cg];
            ACC4(a0, a1, a2, a3, u, w)
        }
    }

    float acc[8] = {a0.x, a0.y, a1.x, a1.y, a2.x, a2.y, a3.x, a3.y};
#pragma unroll
    for (int j = 0; j < 8; ++j) {
        acc[j] += __shfl_down(acc[j], 32);
        acc[j] += __shfl_down(acc[j], 16);
    }

    float d = 0.f;
    if (lane < 16) {
        float4 b0 = ((const float4*)bias)[cg * 2];
        float4 b1 = ((const float4*)bias)[cg * 2 + 1];
        acc[0] += bflo(hn.x); acc[1] += bfhi(hn.x);
        acc[2] += bflo(hn.y); acc[3] += bfhi(hn.y);
        acc[4] += bflo(hn.z); acc[5] += bfhi(hn.z);
        acc[6] += bflo(hn.w); acc[7] += bfhi(hn.w);
        float v[8];
        v[0] = fmaxf(fmaf(dnv, acc[0], b0.x), 0.f);
        v[1] = fmaxf(fmaf(dnv, acc[1], b0.y), 0.f);
        v[2] = fmaxf(fmaf(dnv, acc[2], b0.z), 0.f);
        v[3] = fmaxf(fmaf(dnv, acc[3], b0.w), 0.f);
        v[4] = fmaxf(fmaf(dnv, acc[4], b1.x), 0.f);
        v[5] = fmaxf(fmaf(dnv, acc[5], b1.y), 0.f);
        v[6] = fmaxf(fmaf(dnv, acc[6], b1.z), 0.f);
        v[7] = fmaxf(fmaf(dnv, acc[7], b1.w), 0.f);
        float4 w0v = ((const float4*)Wl)[cg * 2];
        float4 w1v = ((const float4*)Wl)[cg * 2 + 1];
        d = v[0] * w0v.x + v[1] * w0v.y + v[2] * w0v.z + v[3] * w0v.w
          + v[4] * w1v.x + v[5] * w1v.y + v[6] * w1v.z + v[7] * w1v.w;
#pragma unroll
        for (int off = 8; off > 0; off >>= 1) d += __shfl_down(d, off, 16);
        if (lane == 0) out[n] = d + bl[0];
    }
}

extern "C" void kernel_launch(void* const* d_in, const int* in_sizes, int n_in,
                              void* d_out, int out_size, void* d_ws, size_t ws_size,
                              hipStream_t stream) {
    const float* w_x = (const float*)d_in[0];
    const int*   ei  = (const int*)d_in[1];
    const float* ew  = (const float*)d_in[2];
    const float* W1  = (const float*)d_in[3];
    const float* b1  = (const float*)d_in[4];
    const float* W2  = (const float*)d_in[5];
    const float* b2  = (const float*)d_in[6];
    const float* Wl  = (const float*)d_in[7];
    const float* bl  = (const float*)d_in[8];
    float* out = (float*)d_out;

    // ws: H1[NN*128 bf16] H2[NN*128 bf16] flag(+pad) dinv[NN]
    //     cursor[NN] bucket[NN*CAP u32] Wf1/Wf2[16384 u16]   (~65 MB)
    u16*      H1   = (u16*)d_ws;
    u16*      H2   = H1 + (size_t)NN * 128;
    unsigned* flag = (unsigned*)(H2 + (size_t)NN * 128);
    float*    dinv = (float*)(flag + 2);
    int*      cursor = (int*)(dinv + NN);
    unsigned* bucket = (unsigned*)(cursor + NN);
    u16*      Wf1  = (u16*)(bucket + (size_t)NN * CAP);
    u16*      Wf2  = Wf1 + 16384;

    const int BLK = 256;
    const int GA  = NN * 64 / BLK;     // 25000 head-agg blocks

    init_kernel<<<GN + 17, BLK, 0, stream>>>(cursor, flag, (const unsigned*)ei,
                                             W1, W2, Wf1, Wf2);
    fill_kernel<<<FILLB, BLK, 0, stream>>>(ei, flag, ew, cursor, bucket);
    gemm1_kernel<<<GEMMB, BLK, 0, stream>>>(w_x, Wf1, H1, cursor, bucket, dinv);
    agg_gemm_kernel<<<AGB, BLK, 0, stream>>>(cursor, bucket, H1, dinv, b1, Wf2, H2);
    agg_head_kernel<<<GA, BLK, 0, stream>>>(cursor, bucket, H2, dinv, b2, Wl, bl, out);
}

// Round 3
// 221.901 us; speedup vs baseline: 1.0997x; 1.0342x over previous
//
#include <hip/hip_runtime.h>
#include <math.h>

#define NN 100000
#define NE 600000
#define CAP 32          // bucket capacity/node; P(Poisson(6) >= 32) ~ 1e-15
#define GN 391          // ceil(NN/256)
#define GEMMB 782       // ceil(NN/128)
#define AGB 1563        // ceil(NN/64)  -- agg_gemm: 64 nodes/block
#define FILLB 2344      // ceil(NE/256)
// D = 128 fixed

typedef unsigned short u16;
typedef unsigned long long u64;
typedef __attribute__((ext_vector_type(8))) short bf16x8;
typedef __attribute__((ext_vector_type(4))) float f32x4;
typedef __attribute__((ext_vector_type(2))) float f32x2;

union U16x8 { uint4 u; bf16x8 h; };

__device__ __forceinline__ float bflo(unsigned w) { return __uint_as_float(w << 16); }
__device__ __forceinline__ float bfhi(unsigned w) { return __uint_as_float(w & 0xFFFF0000u); }
__device__ __forceinline__ u16 f2bf(float f) {  // round-to-nearest-even
    unsigned u = __float_as_uint(f);
    return (u16)((u + 0x7FFFu + ((u >> 16) & 1u)) >> 16);
}
__device__ __forceinline__ unsigned pack2(float a, float b) {
    return (unsigned)f2bf(a) | ((unsigned)f2bf(b) << 16);
}
__device__ __forceinline__ f32x2 unpk2(unsigned u) {
    f32x2 r; r.x = __uint_as_float(u << 16); r.y = __uint_as_float(u & 0xFFFF0000u);
    return r;
}
// bucket entry: src(17b) << 15 | bf16-weight[14:0] (sign always 0 for ew in [0,1])
__device__ __forceinline__ float bfw(unsigned e) {
    return __uint_as_float((e & 0x7FFFu) << 16);
}
__device__ __forceinline__ int ld_idx(const int* __restrict__ ei, unsigned is32, int pos) {
    return is32 ? ei[pos] : ei[2 * pos];  // int64: little-endian low word
}

// ---------- W -> bf16 fragment-order block (8 blocks of 256 thr per W) ----------
// Tile (ct,kc): lane holds W[kc*32+(lane>>4)*8+j][ct*16+(lane&15)], j=0..7.
__device__ __forceinline__ void wconv_block(const float* __restrict__ W, u16* __restrict__ Wf,
                                            int blk, int tid) {
    int t = blk * 256 + tid;   // 0..2047
    int lane = t & 63, tile = t >> 6;
    int n = (tile >> 2) * 16 + (lane & 15);
    int k0 = (tile & 3) * 32 + (lane >> 4) * 8;
#pragma unroll
    for (int j = 0; j < 8; ++j) Wf[tile * 512 + lane * 8 + j] = f2bf(W[(k0 + j) * 128 + n]);
}

// ---------- init: zero cursor | detect int32-vs-int64 | wconv W1/W2 ----------
__global__ __launch_bounds__(256) void init_kernel(
    int* __restrict__ cursor, unsigned* __restrict__ flag, const unsigned* __restrict__ ei,
    const float* __restrict__ W1, const float* __restrict__ W2,
    u16* __restrict__ Wf1, u16* __restrict__ Wf2)
{
    __shared__ unsigned red[256];
    int b = blockIdx.x, tid = threadIdx.x;
    if (b < GN) {
        int i = b * 256 + tid;
        if (i < NN) cursor[i] = 0;
    } else if (b == GN) {
        unsigned v = 0;
        for (int i = tid; i < 4096; i += 256) v |= ei[2 * i + 1];
        red[tid] = v;
        __syncthreads();
        for (int o = 128; o > 0; o >>= 1) {
            if (tid < o) red[tid] |= red[tid + o];
            __syncthreads();
        }
        if (tid == 0) *flag = red[0] ? 1u : 0u;   // nonzero -> int32 storage
    } else if (b <= GN + 8) {
        wconv_block(W1, Wf1, b - GN - 1, tid);
    } else {
        wconv_block(W2, Wf2, b - GN - 9, tid);
    }
}

// ---------- fill: ONE u32 cursor atomic per edge + 4B bucket store ----------
// Runs ALONE: its cursor/bucket working set must own the L2 (r7/r12 lesson).
// ~40 us = device returning-atomic throughput floor (probed 1/thread, 2/thread, fused).
__global__ __launch_bounds__(256) void fill_kernel(
    const int* __restrict__ ei, const unsigned* __restrict__ flag,
    const float* __restrict__ ew, int* __restrict__ cursor, unsigned* __restrict__ bucket)
{
    int e = blockIdx.x * 256 + threadIdx.x;
    if (e < NE) {
        unsigned is32 = *flag;
        int s = ld_idx(ei, is32, e);
        int d = ld_idx(ei, is32, NE + e);
        unsigned wq = (unsigned)f2bf(ew[e]) & 0x7FFFu;   // bf16, sign bit 0
        int slot = atomicAdd(&cursor[d], 1);
        if (slot < CAP) bucket[(size_t)d * CAP + slot] = ((unsigned)s << 15) | wq;
    }
}

// ---------- gemm1: fused unpack (dinv from buckets) + H1 = diag(dinv) * (X @ W1) ----------
// Phase 0: 2 threads/node sum bucket weights -> dinv + clamped cursor (globals still
//          needed by both agg kernels) + 512B LDS copy for the row scale.
// Phase 1: transposed MFMA gemm; dn from LDS. 32 nodes/wave (probed optimum for the
//          pure coalesced-input gemm).
__global__ __launch_bounds__(256) void gemm1_kernel(
    const float* __restrict__ X, const u16* __restrict__ Wf, u16* __restrict__ H,
    int* __restrict__ cursor, const unsigned* __restrict__ bucket,
    float* __restrict__ dinv)
{
    __shared__ float Ldn[128];
    const int tid = threadIdx.x;
    const unsigned blockBase = blockIdx.x * 128u;

    {   // phase 0: weighted degree -> dinv
        unsigned ni = (unsigned)tid >> 1, p = (unsigned)tid & 1;
        unsigned gn = blockBase + ni;
        if (gn < NN) {
            int c = cursor[gn];
            if (c > CAP) c = CAP;
            float s = 0.f;
            const size_t base = (size_t)gn * CAP;
            for (int i = (int)p; i < c; i += 2) s += bfw(bucket[base + i]);
            s += __shfl_xor(s, 1);
            if (p == 0) {
                cursor[gn] = c;                  // clamp for agg kernels
                float dv = rsqrtf(s + 1.0f);
                dinv[gn] = dv;
                Ldn[ni] = dv;
            }
        }
    }
    __syncthreads();

    const int wave = tid >> 6, lane = tid & 63;
    const int m = lane & 15, q = lane >> 4;
    const unsigned nodeBase = blockBase + wave * 32;

    U16x8 xf[2][4];
    float dn[2];
#pragma unroll
    for (int mt = 0; mt < 2; ++mt) {
        unsigned row = nodeBase + mt * 16 + m;
        unsigned rowc = row < NN ? row : NN - 1;
        dn[mt] = Ldn[rowc - blockBase];
#pragma unroll
        for (int kc = 0; kc < 4; ++kc) {
            float4 a = ((const float4*)X)[rowc * 32u + kc * 8 + q * 2];
            float4 b = ((const float4*)X)[rowc * 32u + kc * 8 + q * 2 + 1];
            xf[mt][kc].u = make_uint4(pack2(a.x, a.y), pack2(a.z, a.w),
                                      pack2(b.x, b.y), pack2(b.z, b.w));
        }
    }

#pragma unroll
    for (int ct = 0; ct < 8; ++ct) {
        U16x8 wfr[4];
#pragma unroll
        for (int kc = 0; kc < 4; ++kc)
            wfr[kc].u = ((const uint4*)Wf)[(ct * 4 + kc) * 64 + lane];
#pragma unroll
        for (int mt = 0; mt < 2; ++mt) {
            f32x4 acc = (f32x4){0.f, 0.f, 0.f, 0.f};
#pragma unroll
            for (int kc = 0; kc < 4; ++kc)
                acc = __builtin_amdgcn_mfma_f32_16x16x32_bf16(
                    wfr[kc].h, xf[mt][kc].h, acc, 0, 0, 0);
            unsigned node = nodeBase + mt * 16 + m;
            if (node < NN) {
                float s = dn[mt];
                uint2 o = make_uint2(pack2(acc[0] * s, acc[1] * s),
                                     pack2(acc[2] * s, acc[3] * s));
                *(uint2*)&H[(size_t)node * 128 + ct * 16 + q * 4] = o;
            }
        }
    }
}

// ---------- agg_gemm: layer-1 aggregate (lane-local channels) -> LDS -> H2 = Xs @ W2 ----
// R3 restructure: R2 showed VALUBusy 50% @ 2.8 waves/SIMD + 100k LDS bank conflicts --
// the eo-split + 16-shuffle reduce + lane<16 epilogue was the limiter, not wave count.
// Now each lane owns 2 channels (f32x2) of the full 128-wide row: per edge ONE
// global_load_dword/lane (same 256B/edge coalescing), NO cross-lane reduce, NO
// divergence. Bucket entries: one coalesced 128B load -> __builtin_amdgcn_readlane
// broadcast (SALU). Next node's entry/cnt/dinv prefetched one iteration ahead.
// 12 straight-line slots (P(deg>12) ~ 0.9%) + dynamic-readlane tail.
// LDS: row = 64 u32; write lane->uint col (lane>>2)^(row&7) swizzle (bank-perfect);
// read path (uint4 + same XOR) unchanged from R2. No barrier: wave reads own rows.
__global__ __launch_bounds__(256) void agg_gemm_kernel(
    const int* __restrict__ cnt, const unsigned* __restrict__ bucket,
    const u16* __restrict__ H, const float* __restrict__ dinv,
    const float* __restrict__ bias, const u16* __restrict__ Wf,
    u16* __restrict__ Hout)
{
    __shared__ unsigned Xs32[4096];   // 64 rows x 64 u32 = 16 KB
    const int tid = threadIdx.x;
    const int wave = tid >> 6, lane = tid & 63;
    const unsigned blockBase = blockIdx.x * 64u;
    const unsigned* H32 = (const unsigned*)H;

    float2 bias2 = ((const float2*)bias)[lane];   // channels 2*lane, 2*lane+1

    unsigned nb = blockBase + (unsigned)wave * 16u;
    unsigned n0 = nb < NN ? nb : NN - 1;
    unsigned lane_entry = bucket[n0 * CAP + (lane & 31)];
    int cpre = cnt[n0];
    float dpre = dinv[n0];

    for (int j = 0; j < 16; ++j) {
        unsigned n = nb + j;
        unsigned ncl = n < NN ? n : NN - 1;
        unsigned entry = lane_entry;
        int c = cpre;
        float dnv = dpre;
        unsigned hn = H32[(size_t)ncl * 64u + lane];
        if (j < 15) {   // prefetch next node's metadata (covers entry->gather dep)
            unsigned n1 = nb + j + 1;
            n1 = n1 < NN ? n1 : NN - 1;
            lane_entry = bucket[n1 * CAP + (lane & 31)];
            cpre = cnt[n1];
            dpre = dinv[n1];
        }

        unsigned uu[12];
        float ww[12];
#pragma unroll
        for (int i = 0; i < 12; ++i) {
            unsigned e = (unsigned)__builtin_amdgcn_readlane((int)entry, i);
            bool val = i < c;
            ww[i] = val ? bfw(e) : 0.f;
            unsigned src = val ? (e >> 15) : ncl;      // invalid -> hot self row
            uu[i] = H32[(size_t)src * 64u + lane];
        }
        f32x2 acc = unpk2(hn);
#pragma unroll
        for (int i = 0; i < 12; ++i) {
            f32x2 wv; wv.x = ww[i]; wv.y = ww[i];
            acc = __builtin_elementwise_fma(unpk2(uu[i]), wv, acc);
        }
        if (c > 12) {                 // rare tail (~1% of nodes)
            for (int i = 12; i < c; ++i) {
                unsigned e = (unsigned)__builtin_amdgcn_readlane((int)entry, i);
                f32x2 wv; wv.x = bfw(e); wv.y = wv.x;
                unsigned u = H32[(size_t)(e >> 15) * 64u + lane];
                acc = __builtin_elementwise_fma(unpk2(u), wv, acc);
            }
        }

        float vx = fmaxf(fmaf(dnv, acc.x, bias2.x), 0.f);
        float vy = fmaxf(fmaf(dnv, acc.y, bias2.y), 0.f);
        unsigned o = pack2(vx * dnv, vy * dnv);       // X1' = relu(row)*dinv, bf16x2
        unsigned r = (unsigned)wave * 16u + (unsigned)j;
        Xs32[r * 64u + ((((unsigned)lane >> 2) ^ (r & 7u)) << 2) + ((unsigned)lane & 3u)] = o;
    }
    // no __syncthreads: each wave reads only the 16 rows it wrote (in-wave lgkmcnt order)

    const int m = lane & 15, q = lane >> 4;
    U16x8 xf[4];
    {
        unsigned r = (unsigned)wave * 16u + m;
#pragma unroll
        for (int kc = 0; kc < 4; ++kc)
            xf[kc].u = ((const uint4*)Xs32)[r * 16u + ((unsigned)(kc * 4 + q) ^ (r & 7u))];
    }
#pragma unroll
    for (int ct = 0; ct < 8; ++ct) {
        U16x8 wfr[4];
#pragma unroll
        for (int kc = 0; kc < 4; ++kc)
            wfr[kc].u = ((const uint4*)Wf)[(ct * 4 + kc) * 64 + lane];
        f32x4 acc = (f32x4){0.f, 0.f, 0.f, 0.f};
#pragma unroll
        for (int kc = 0; kc < 4; ++kc)
            acc = __builtin_amdgcn_mfma_f32_16x16x32_bf16(
                wfr[kc].h, xf[kc].h, acc, 0, 0, 0);
        unsigned node = blockBase + (unsigned)wave * 16u + m;
        if (node < NN) {
            uint2 o = make_uint2(pack2(acc[0], acc[1]), pack2(acc[2], acc[3]));
            *(uint2*)&Hout[(size_t)node * 128 + ct * 16 + q * 4] = o;
        }
    }
}

// ---------- agg head: 1 wave/node, lane-local channels (same R3 structure) ----------
// out[n] = relu(dinv[n]*(sum w*H2[src] + H2[n]) + b2) . Wl + bl
__global__ __launch_bounds__(256) void agg_head_kernel(
    const int* __restrict__ cnt, const unsigned* __restrict__ bucket,
    const u16* __restrict__ H, const float* __restrict__ dinv,
    const float* __restrict__ bias, const float* __restrict__ Wl,
    const float* __restrict__ bl, float* __restrict__ out)
{
    unsigned t = blockIdx.x * 256 + threadIdx.x;
    unsigned n = t >> 6;
    int lane = (int)(t & 63);
    const unsigned* H32 = (const unsigned*)H;

    unsigned lane_entry = bucket[n * CAP + (lane & 31)];
    const int c = cnt[n];
    unsigned hn = H32[(size_t)n * 64u + lane];
    float dnv = dinv[n];

    unsigned uu[12];
    float ww[12];
#pragma unroll
    for (int i = 0; i < 12; ++i) {
        unsigned e = (unsigned)__builtin_amdgcn_readlane((int)lane_entry, i);
        bool val = i < c;
        ww[i] = val ? bfw(e) : 0.f;
        unsigned src = val ? (e >> 15) : n;
        uu[i] = H32[(size_t)src * 64u + lane];
    }
    f32x2 acc = unpk2(hn);
#pragma unroll
    for (int i = 0; i < 12; ++i) {
        f32x2 wv; wv.x = ww[i]; wv.y = ww[i];
        acc = __builtin_elementwise_fma(unpk2(uu[i]), wv, acc);
    }
    if (c > 12) {                 // rare tail (~1% of nodes)
        for (int i = 12; i < c; ++i) {
            unsigned e = (unsigned)__builtin_amdgcn_readlane((int)lane_entry, i);
            f32x2 wv; wv.x = bfw(e); wv.y = wv.x;
            unsigned u = H32[(size_t)(e >> 15) * 64u + lane];
            acc = __builtin_elementwise_fma(unpk2(u), wv, acc);
        }
    }

    float2 bias2 = ((const float2*)bias)[lane];
    float2 wl2   = ((const float2*)Wl)[lane];
    float vx = fmaxf(fmaf(dnv, acc.x, bias2.x), 0.f);
    float vy = fmaxf(fmaf(dnv, acc.y, bias2.y), 0.f);
    float d = vx * wl2.x + vy * wl2.y;
#pragma unroll
    for (int off = 32; off > 0; off >>= 1) d += __shfl_down(d, off);
    if (lane == 0) out[n] = d + bl[0];
}

extern "C" void kernel_launch(void* const* d_in, const int* in_sizes, int n_in,
                              void* d_out, int out_size, void* d_ws, size_t ws_size,
                              hipStream_t stream) {
    const float* w_x = (const float*)d_in[0];
    const int*   ei  = (const int*)d_in[1];
    const float* ew  = (const float*)d_in[2];
    const float* W1  = (const float*)d_in[3];
    const float* b1  = (const float*)d_in[4];
    const float* W2  = (const float*)d_in[5];
    const float* b2  = (const float*)d_in[6];
    const float* Wl  = (const float*)d_in[7];
    const float* bl  = (const float*)d_in[8];
    float* out = (float*)d_out;

    // ws: H1[NN*128 bf16] H2[NN*128 bf16] flag(+pad) dinv[NN]
    //     cursor[NN] bucket[NN*CAP u32] Wf1/Wf2[16384 u16]   (~65 MB)
    u16*      H1   = (u16*)d_ws;
    u16*      H2   = H1 + (size_t)NN * 128;
    unsigned* flag = (unsigned*)(H2 + (size_t)NN * 128);
    float*    dinv = (float*)(flag + 2);
    int*      cursor = (int*)(dinv + NN);
    unsigned* bucket = (unsigned*)(cursor + NN);
    u16*      Wf1  = (u16*)(bucket + (size_t)NN * CAP);
    u16*      Wf2  = Wf1 + 16384;

    const int BLK = 256;
    const int GA  = NN * 64 / BLK;     // 25000 head-agg blocks

    init_kernel<<<GN + 17, BLK, 0, stream>>>(cursor, flag, (const unsigned*)ei,
                                             W1, W2, Wf1, Wf2);
    fill_kernel<<<FILLB, BLK, 0, stream>>>(ei, flag, ew, cursor, bucket);
    gemm1_kernel<<<GEMMB, BLK, 0, stream>>>(w_x, Wf1, H1, cursor, bucket, dinv);
    agg_gemm_kernel<<<AGB, BLK, 0, stream>>>(cursor, bucket, H1, dinv, b1, Wf2, H2);
    agg_head_kernel<<<GA, BLK, 0, stream>>>(cursor, bucket, H2, dinv, b2, Wl, bl, out);
}